// Round 2
// baseline (11666.172 us; speedup 1.0000x reference)
//
#include <hip/hip_runtime.h>

// 2-layer LSTM, B=64, T=1024, D_IN=256, H=512, fp32 in/out.
// R5: R4 structure (transposed [k][b] h buffers, full-step prefetch, flat flag
// barrier) with ONE change:
//  - h fragment loads are now PLAIN CACHED loads (L1/L2-cacheable) instead of
//    sc1 agent-atomic loads. Staleness is handled by a single AGENT-scope
//    acquire fence (buffer_inv) per block per step, issued by wave 0 after the
//    grid-barrier poll and before the closing __syncthreads. All producer
//    write-through stores reached L3 before flags were set, so any L2 refill
//    after the inv pulls fresh data; the 32 blocks of an XCD now share one L3
//    fill per line instead of 32 (L3 broadcast traffic ~48MB/step -> ~3MB/step).
// Producer side unchanged: relaxed AGENT write-through stores (never dirty in
// L2), vmcnt drained before flag store; flag polls remain sc1 atomic loads.

#define BB   64
#define TT   1024
#define DIN  256
#define HH   512
#define K0   768     // [h0_prev(512) | x_t(256)]
#define K1   1024    // [h1_prev(512) | h0_t(512)]
#define NTHR 512

typedef float f32x4 __attribute__((ext_vector_type(4)));
typedef short short8 __attribute__((ext_vector_type(8)));

union S8U4 { short8 s; unsigned u[4]; };
union RawU { unsigned u[8]; f32x4 v[2]; };   // 8 packed h-words OR 8 x-floats

__device__ __forceinline__ void splitf(float f, short& h, short& l) {
    const unsigned u = __float_as_uint(f);
    const float fh = __uint_as_float(u & 0xffff0000u);
    h = (short)(u >> 16);
    l = (short)(__float_as_uint(f - fh) >> 16);
}

__device__ __forceinline__ void split8(f32x4 a, f32x4 b, short8& hi, short8& lo) {
#pragma unroll
    for (int j = 0; j < 4; ++j) {
        short h0, l0, h1, l1;
        splitf(a[j], h0, l0);
        splitf(b[j], h1, l1);
        hi[j] = h0; lo[j] = l0;
        hi[j + 4] = h1; lo[j + 4] = l1;
    }
}

__device__ __forceinline__ unsigned packhl(float f) {
    const unsigned u = __float_as_uint(f);
    const float fh = __uint_as_float(u & 0xffff0000u);
    const unsigned l = __float_as_uint(f - fh) >> 16;
    return (u >> 16) | (l << 16);     // bytes 0-1: hi bf16, bytes 2-3: lo bf16
}

__global__ __launch_bounds__(NTHR, 2) void lstm_fused(
    const float* __restrict__ x,
    const float* __restrict__ W0, const float* __restrict__ b0v,
    const float* __restrict__ W1, const float* __restrict__ b1v,
    float* __restrict__ out, unsigned* __restrict__ hws, unsigned* __restrict__ bar)
{
    __shared__ float Red[8][16][68];    // per-wave K-partials, padded (34.8 KB)
    __shared__ float Gb[BB][17];        // gates regroup (4.4 KB)
    __shared__ float biasl[16];

    const int tid   = threadIdx.x;
    const int bid   = blockIdx.x;
    const int layer = bid >> 7;
    const int hbase = (bid & 127) << 2;

    const float* Wm = layer ? W1 : W0;
    const float* bv = layer ? b1v : b0v;
    const int K     = layer ? K1 : K0;

    // packed (hi|lo) h buffers, TRANSPOSED: [2 parities][512 k][64 b] u32
    unsigned* HP0 = hws;
    unsigned* HP1 = hws + 2 * BB * HH;

    if (tid < 16)
        biasl[tid] = bv[(tid >> 2) * HH + hbase + (tid & 3)];

    const int w     = tid >> 6;        // wave 0..7 (K-slice owner)
    const int lane  = tid & 63;
    const int quad  = lane >> 4;       // 0..3
    const int lm    = lane & 15;       // fragment row (m or n)
    const int kbase = w << 7;          // wave's K offset (128 each)
    const int grow  = (lm >> 2) * HH + hbase + (lm & 3);

    // ---- persistent W fragments: hi/lo bf16, 4 k-steps of 32 ----
    short8 whi[4], wlo[4];
#pragma unroll
    for (int ks = 0; ks < 4; ++ks) {
        short8 hi = {0, 0, 0, 0, 0, 0, 0, 0};
        short8 lo = {0, 0, 0, 0, 0, 0, 0, 0};
        const int kb = kbase + ks * 32;
        if (kb < K) {
            const int k0 = kb + quad * 8;
            const float* p = Wm + (size_t)grow * K + k0;
            split8(*(const f32x4*)p, *(const f32x4*)(p + 4), hi, lo);
        }
        whi[ks] = hi; wlo[ks] = lo;
    }
    __syncthreads();

    float creg = 0.0f;                 // persistent cell state (tid<256)
    unsigned epoch = 0;
    const size_t YOFF = (size_t)BB * TT * HH;

    for (int s = 0; s <= TT; ++s) {
        const bool active = layer ? (s >= 1) : (s < TT);
        if (active) {
            const int t   = layer ? (s - 1) : s;
            const int par = (s & 1) * BB * HH;
            const unsigned* hp = (layer ? HP1 : HP0) + par;
            const unsigned* hc = HP0 + par;   // layer1: h0 of current t

            // ---- PHASE 1: issue ALL fragment loads (deep vmcnt pipeline) ----
            // Plain cached loads: L2 was invalidated after the last grid
            // barrier, so first touch per XCD refills from L3, rest hit L2.
            RawU raw[4][4];   // [ks][nt], 8 dwords each: 128 VGPRs in flight
#pragma unroll
            for (int ks = 0; ks < 4; ++ks) {
                const int kb = kbase + ks * 32;
                if (kb < K) {
                    const int k0 = kb + quad * 8;
                    if (kb < HH) {
#pragma unroll
                        for (int nt = 0; nt < 4; ++nt) {
                            const int n = (nt << 4) + lm;
                            const unsigned* p = hp + (size_t)k0 * BB + n;
#pragma unroll
                            for (int j = 0; j < 8; ++j)
                                raw[ks][nt].u[j] = p[(size_t)j * BB];
                        }
                    } else if (layer) {
#pragma unroll
                        for (int nt = 0; nt < 4; ++nt) {
                            const int n = (nt << 4) + lm;
                            const unsigned* p = hc + (size_t)(k0 - HH) * BB + n;
#pragma unroll
                            for (int j = 0; j < 8; ++j)
                                raw[ks][nt].u[j] = p[(size_t)j * BB];
                        }
                    } else {
#pragma unroll
                        for (int nt = 0; nt < 4; ++nt) {
                            const int n = (nt << 4) + lm;
                            const float* p = x + ((size_t)n * TT + t) * DIN + (k0 - HH);
                            raw[ks][nt].v[0] = *(const f32x4*)p;
                            raw[ks][nt].v[1] = *(const f32x4*)(p + 4);
                        }
                    }
                }
            }

            // ---- PHASE 2: unpack + MFMA (consumes loads in issue order) ----
            f32x4 acc[4];
#pragma unroll
            for (int nt = 0; nt < 4; ++nt) acc[nt] = (f32x4){0.f, 0.f, 0.f, 0.f};

#pragma unroll
            for (int ks = 0; ks < 4; ++ks) {
                const int kb = kbase + ks * 32;
                if (kb < K) {
#pragma unroll
                    for (int nt = 0; nt < 4; ++nt) {
                        short8 chi, clo;
                        if (!layer && kb >= HH) {
                            split8(raw[ks][nt].v[0], raw[ks][nt].v[1], chi, clo);
                        } else {
                            S8U4 hi, lo;
#pragma unroll
                            for (int j2 = 0; j2 < 4; ++j2) {
                                const unsigned u0 = raw[ks][nt].u[2 * j2];
                                const unsigned u1 = raw[ks][nt].u[2 * j2 + 1];
                                hi.u[j2] = __builtin_amdgcn_perm(u1, u0, 0x05040100u);
                                lo.u[j2] = __builtin_amdgcn_perm(u1, u0, 0x07060302u);
                            }
                            chi = hi.s; clo = lo.s;
                        }
                        acc[nt] = __builtin_amdgcn_mfma_f32_16x16x32_bf16(whi[ks], chi, acc[nt], 0, 0, 0);
                        acc[nt] = __builtin_amdgcn_mfma_f32_16x16x32_bf16(whi[ks], clo, acc[nt], 0, 0, 0);
                        acc[nt] = __builtin_amdgcn_mfma_f32_16x16x32_bf16(wlo[ks], chi, acc[nt], 0, 0, 0);
                    }
                }
            }

            // ---- dump K-partials: D[m=quad*4+r][n=nt*16+lm] ----
#pragma unroll
            for (int nt = 0; nt < 4; ++nt)
#pragma unroll
                for (int r = 0; r < 4; ++r)
                    Red[w][quad * 4 + r][(nt << 4) + lm] = acc[nt][r];
            __syncthreads();
            // ---- 8-way reduce + bias ----
            {
                const int row = tid & 15, b0 = tid >> 4;
                float s0 = biasl[row], s1 = biasl[row];
#pragma unroll
                for (int ww = 0; ww < 8; ++ww) {
                    s0 += Red[ww][row][b0];
                    s1 += Red[ww][row][b0 + 32];
                }
                Gb[b0][row] = s0;
                Gb[b0 + 32][row] = s1;
            }
            __syncthreads();
            // ---- cell: 256 threads, one (b, hh) each; c stays in creg ----
            if (tid < 256) {
                const int b   = tid & 63;
                const int hh2 = tid >> 6;
                const float ig = Gb[b][hh2];
                const float fg = Gb[b][4 + hh2];
                const float gg = Gb[b][8 + hh2];
                const float og = Gb[b][12 + hh2];
                const float si = 1.0f / (1.0f + __expf(-ig));
                const float sf = 1.0f / (1.0f + __expf(-fg));
                const float so = 1.0f / (1.0f + __expf(-og));
                const float c  = sf * creg + si * tanhf(gg);
                creg = c;
                const float h  = so * tanhf(c);
                const int hidx = hbase + hh2;
                const int wpar = ((s + 1) & 1) * BB * HH;
                const unsigned packed = packhl(h);
                // transposed store: consecutive tids (b) -> consecutive addrs
                if (layer == 0) {
                    __hip_atomic_store(&HP0[wpar + hidx * BB + b], packed,
                                       __ATOMIC_RELAXED, __HIP_MEMORY_SCOPE_AGENT);
                    if (t == TT - 1) {
                        out[YOFF + (size_t)b * HH + hidx] = h;                 // h_n[0]
                        out[YOFF + 2 * BB * HH + (size_t)b * HH + hidx] = c;   // c_n[0]
                    }
                } else {
                    out[((size_t)b * TT + t) * HH + hidx] = h;                 // y[b,t,:]
                    __hip_atomic_store(&HP1[wpar + hidx * BB + b], packed,
                                       __ATOMIC_RELAXED, __HIP_MEMORY_SCOPE_AGENT);
                    if (t == TT - 1) {
                        out[YOFF + BB * HH + (size_t)b * HH + hidx] = h;       // h_n[1]
                        out[YOFF + 3 * BB * HH + (size_t)b * HH + hidx] = c;   // c_n[1]
                    }
                }
            }
        }
        // ---- flat flag barrier: store-only, per-block monotonic epochs ----
        if (s < TT) {
            __syncthreads();   // drains each thread's vmcnt -> sc1 stores visible
            ++epoch;
            if (tid == 0) {
                asm volatile("s_waitcnt vmcnt(0)" ::: "memory");
                __hip_atomic_store(&bar[bid], epoch,
                                   __ATOMIC_RELAXED, __HIP_MEMORY_SCOPE_AGENT);
            }
            if (tid < 256) {   // 4 waves, each poll covers 64 consecutive flags
                while (__hip_atomic_load(&bar[tid], __ATOMIC_RELAXED,
                                         __HIP_MEMORY_SCOPE_AGENT) < epoch)
                    __builtin_amdgcn_s_sleep(1);
            }
            // One agent-acquire fence per block (wave 0): invalidates stale
            // L1/L2 lines so this step's plain cached h loads refill from L3.
            // All producers' write-throughs reached L3 before their flags were
            // observed above, so post-inv refills are guaranteed fresh.
            if (tid < 64)
                __builtin_amdgcn_fence(__ATOMIC_ACQUIRE, "agent");
            __syncthreads();
        }
    }
}

extern "C" void kernel_launch(void* const* d_in, const int* in_sizes, int n_in,
                              void* d_out, int out_size, void* d_ws, size_t ws_size,
                              hipStream_t stream) {
    (void)in_sizes; (void)n_in; (void)out_size; (void)ws_size;
    const float* x  = (const float*)d_in[0];
    const float* W0 = (const float*)d_in[1];
    const float* b0 = (const float*)d_in[2];
    const float* W1 = (const float*)d_in[3];
    const float* b1 = (const float*)d_in[4];
    float* out = (float*)d_out;
    unsigned* hws = (unsigned*)d_ws;  // 2 buffers x [2][512][64] u32 = 512 KB
    unsigned* bar = (unsigned*)((char*)d_ws + 2 * 2 * 64 * 512 * sizeof(unsigned));

    hipMemsetAsync(d_ws, 0, 2 * 2 * 64 * 512 * sizeof(unsigned) + 4096, stream);

    void* args[] = { (void*)&x, (void*)&W0, (void*)&b0, (void*)&W1, (void*)&b1,
                     (void*)&out, (void*)&hws, (void*)&bar };
    hipLaunchCooperativeKernel(reinterpret_cast<const void*>(lstm_fused),
                               dim3(256), dim3(512), args, 0u, stream);
}

// Round 3
// 11092.863 us; speedup vs baseline: 1.0517x; 1.0517x over previous
//
#include <hip/hip_runtime.h>

// 2-layer LSTM, B=64, T=1024, D_IN=256, H=512, fp32 in/out.
// R6: revert R5's fence (neutral-negative); back to R4's verified memory model
// (sc1 agent reads, write-through relaxed agent stores, flat flag barrier).
// Changes vs R4:
//  - h buffers retiled: [parity][k>>2][b][k&3] u32. Consumer fragment = exactly
//    2 x global_load_dwordx4 (32 loads/lane/step instead of 128 dwords);
//    producer writes ONE dense contiguous 1KB region per block per step.
//  - h loads via inline-asm global_load_dwordx4 ... sc1: the 128 asm-output
//    VGPRs force a true full-step prefetch (R4's compiler-scheduled version
//    allocated only 124 VGPRs => serialized L3 round trips). Single explicit
//    s_waitcnt vmcnt(0) + sched_barrier(0) before consumption (rule #18).
//  - cell threads remapped (b=tid>>2, g=tid&3): h store linear in tid.
//  - layer-1 y stores issued AFTER the flag store (drain overlaps the poll).

#define BB   64
#define TT   1024
#define DIN  256
#define HH   512
#define K0   768     // [h0_prev(512) | x_t(256)]
#define K1   1024    // [h1_prev(512) | h0_t(512)]
#define NTHR 512

typedef float f32x4 __attribute__((ext_vector_type(4)));
typedef short short8 __attribute__((ext_vector_type(8)));
typedef unsigned uint4v __attribute__((ext_vector_type(4)));

union S8U4 { short8 s; unsigned u[4]; };
union RawU { unsigned u[8]; uint4v q[2]; f32x4 v[2]; };  // 8 packed h words OR 8 x floats

__device__ __forceinline__ void splitf(float f, short& h, short& l) {
    const unsigned u = __float_as_uint(f);
    const float fh = __uint_as_float(u & 0xffff0000u);
    h = (short)(u >> 16);
    l = (short)(__float_as_uint(f - fh) >> 16);
}

__device__ __forceinline__ void split8(f32x4 a, f32x4 b, short8& hi, short8& lo) {
#pragma unroll
    for (int j = 0; j < 4; ++j) {
        short h0, l0, h1, l1;
        splitf(a[j], h0, l0);
        splitf(b[j], h1, l1);
        hi[j] = h0; lo[j] = l0;
        hi[j + 4] = h1; lo[j + 4] = l1;
    }
}

__device__ __forceinline__ unsigned packhl(float f) {
    const unsigned u = __float_as_uint(f);
    const float fh = __uint_as_float(u & 0xffff0000u);
    const unsigned l = __float_as_uint(f - fh) >> 16;
    return (u >> 16) | (l << 16);     // bytes 0-1: hi bf16, bytes 2-3: lo bf16
}

// sc1 = agent-scope (bypass stale L1/L2, served by L3) -- same policy the
// compiler emits for __hip_atomic_load(...,AGENT), verified in R3/R4.
#define LDX4(dst, ptr, off) \
    asm volatile("global_load_dwordx4 %0, %1, off offset:" #off " sc1" \
                 : "=v"(dst) : "v"(ptr) : "memory")

// One k-step (32 k) for all 4 n-tiles: offsets = nt*256 + half*1024 bytes.
#define LD8(A, R) do { \
    LDX4((R)[0].q[0], (A), 0);    LDX4((R)[0].q[1], (A), 1024); \
    LDX4((R)[1].q[0], (A), 256);  LDX4((R)[1].q[1], (A), 1280); \
    LDX4((R)[2].q[0], (A), 512);  LDX4((R)[2].q[1], (A), 1536); \
    LDX4((R)[3].q[0], (A), 768);  LDX4((R)[3].q[1], (A), 1792); \
} while (0)

__global__ __launch_bounds__(NTHR, 2) void lstm_fused(
    const float* __restrict__ x,
    const float* __restrict__ W0, const float* __restrict__ b0v,
    const float* __restrict__ W1, const float* __restrict__ b1v,
    float* __restrict__ out, unsigned* __restrict__ hws, unsigned* __restrict__ bar)
{
    __shared__ float Red[8][16][68];    // per-wave K-partials, padded (34.8 KB)
    __shared__ float Gb[BB][17];        // gates regroup (4.4 KB)
    __shared__ float biasl[16];

    const int tid   = threadIdx.x;
    const int bid   = blockIdx.x;
    const int layer = bid >> 7;
    const int hbase = (bid & 127) << 2;

    const float* Wm = layer ? W1 : W0;
    const float* bv = layer ? b1v : b0v;
    const int K     = layer ? K1 : K0;

    // packed (hi|lo) h buffers, tiled: [2 parities][k>>2][64 b][k&3] u32
    unsigned* HP0 = hws;
    unsigned* HP1 = hws + 2 * BB * HH;

    if (tid < 16)
        biasl[tid] = bv[(tid >> 2) * HH + hbase + (tid & 3)];

    const int w     = tid >> 6;        // wave 0..7 (K-slice owner)
    const int lane  = tid & 63;
    const int quad  = lane >> 4;       // 0..3
    const int lm    = lane & 15;       // fragment row (m or n)
    const int kbase = w << 7;          // wave's K offset (128 each)
    const int grow  = (lm >> 2) * HH + hbase + (lm & 3);
    const bool isx  = (!layer && kbase >= HH);   // L0 waves 4,5 (x); 6,7 idle

    // ---- persistent W fragments: hi/lo bf16, 4 k-steps of 32 ----
    short8 whi[4], wlo[4];
#pragma unroll
    for (int ks = 0; ks < 4; ++ks) {
        short8 hi = {0, 0, 0, 0, 0, 0, 0, 0};
        short8 lo = {0, 0, 0, 0, 0, 0, 0, 0};
        const int kb = kbase + ks * 32;
        if (kb < K) {
            const int k0 = kb + quad * 8;
            const float* p = Wm + (size_t)grow * K + k0;
            split8(*(const f32x4*)p, *(const f32x4*)(p + 4), hi, lo);
        }
        whi[ks] = hi; wlo[ks] = lo;
    }
    __syncthreads();

    float creg = 0.0f;                 // persistent cell state (tid<256)
    unsigned epoch = 0;
    const size_t YOFF = (size_t)BB * TT * HH;

    for (int s = 0; s <= TT; ++s) {
        const bool active = layer ? (s >= 1) : (s < TT);
        float hdef = 0.0f;             // deferred y value (layer 1)
        if (active) {
            const int t = layer ? (s - 1) : s;
            const unsigned par = (unsigned)(s & 1) * (BB * HH);
            const unsigned* hp = (layer ? HP1 : HP0) + par;
            const unsigned* hc = HP0 + par;   // layer1: h0 of current t

            // ---- PHASE 1: issue ALL loads; asm outputs pin full prefetch ----
            RawU raw[4][4];   // [ks][nt]
            if (layer || kbase < HH) {         // h-type wave (always full range)
                const unsigned* src; int kk;
                if (!layer)          { src = hp; kk = kbase; }        // h0 prev
                else if (kbase < HH) { src = hp; kk = kbase; }        // h1 prev
                else                 { src = hc; kk = kbase - HH; }   // h0 cur
                // byte addr = kk*256 + quad*2048 + lm*16 (+ ks*8192 + imm)
                const char* A = (const char*)src + ((size_t)kk << 8)
                              + (quad << 11) + (lm << 4);
                LD8(A,         raw[0]);
                LD8(A + 8192,  raw[1]);
                LD8(A + 16384, raw[2]);
                LD8(A + 24576, raw[3]);
            } else {                           // x waves (plain cached loads)
#pragma unroll
                for (int ks = 0; ks < 4; ++ks) {
                    const int kb = kbase + ks * 32;
                    if (kb < K0) {
                        const int k0 = kb + quad * 8;
#pragma unroll
                        for (int nt = 0; nt < 4; ++nt) {
                            const int n = (nt << 4) + lm;
                            const float* p = x + ((size_t)n * TT + t) * DIN + (k0 - HH);
                            raw[ks][nt].v[0] = *(const f32x4*)p;
                            raw[ks][nt].v[1] = *(const f32x4*)(p + 4);
                        }
                    }
                }
            }
            asm volatile("s_waitcnt vmcnt(0)" ::: "memory");
            __builtin_amdgcn_sched_barrier(0);   // rule #18: keep MFMA below wait

            // ---- PHASE 2: unpack + MFMA ----
            f32x4 acc[4];
#pragma unroll
            for (int nt = 0; nt < 4; ++nt) acc[nt] = (f32x4){0.f, 0.f, 0.f, 0.f};

#pragma unroll
            for (int ks = 0; ks < 4; ++ks) {
                const int kb = kbase + ks * 32;
                if (kb < K) {
#pragma unroll
                    for (int nt = 0; nt < 4; ++nt) {
                        short8 chi, clo;
                        if (isx) {
                            split8(raw[ks][nt].v[0], raw[ks][nt].v[1], chi, clo);
                        } else {
                            S8U4 hi, lo;
#pragma unroll
                            for (int j2 = 0; j2 < 4; ++j2) {
                                const unsigned u0 = raw[ks][nt].u[2 * j2];
                                const unsigned u1 = raw[ks][nt].u[2 * j2 + 1];
                                hi.u[j2] = __builtin_amdgcn_perm(u1, u0, 0x05040100u);
                                lo.u[j2] = __builtin_amdgcn_perm(u1, u0, 0x07060302u);
                            }
                            chi = hi.s; clo = lo.s;
                        }
                        acc[nt] = __builtin_amdgcn_mfma_f32_16x16x32_bf16(whi[ks], chi, acc[nt], 0, 0, 0);
                        acc[nt] = __builtin_amdgcn_mfma_f32_16x16x32_bf16(whi[ks], clo, acc[nt], 0, 0, 0);
                        acc[nt] = __builtin_amdgcn_mfma_f32_16x16x32_bf16(wlo[ks], chi, acc[nt], 0, 0, 0);
                    }
                }
            }

            // ---- dump K-partials: D[m=quad*4+r][n=nt*16+lm] ----
#pragma unroll
            for (int nt = 0; nt < 4; ++nt)
#pragma unroll
                for (int r = 0; r < 4; ++r)
                    Red[w][quad * 4 + r][(nt << 4) + lm] = acc[nt][r];
            __syncthreads();
            // ---- 8-way reduce + bias ----
            {
                const int row = tid & 15, b0 = tid >> 4;
                float s0 = biasl[row], s1 = biasl[row];
#pragma unroll
                for (int ww = 0; ww < 8; ++ww) {
                    s0 += Red[ww][row][b0];
                    s1 += Red[ww][row][b0 + 32];
                }
                Gb[b0][row] = s0;
                Gb[b0 + 32][row] = s1;
            }
            __syncthreads();
            // ---- cell: 256 threads, (b=tid>>2, g=tid&3); c stays in creg ----
            if (tid < 256) {
                const int b = tid >> 2;
                const int g = tid & 3;
                const float ig = Gb[b][g];
                const float fg = Gb[b][4 + g];
                const float gg = Gb[b][8 + g];
                const float og = Gb[b][12 + g];
                const float si = 1.0f / (1.0f + __expf(-ig));
                const float sf = 1.0f / (1.0f + __expf(-fg));
                const float so = 1.0f / (1.0f + __expf(-og));
                const float c  = sf * creg + si * tanhf(gg);
                creg = c;
                const float h  = so * tanhf(c);
                const unsigned wpar = (unsigned)((s + 1) & 1) * (BB * HH);
                // tiled, linear-in-tid store: [hbase>>2 tile][b][g]
                const unsigned widx = wpar + ((unsigned)(hbase >> 2) << 8) + (b << 2) + g;
                const unsigned packed = packhl(h);
                if (layer == 0) {
                    __hip_atomic_store(&HP0[widx], packed,
                                       __ATOMIC_RELAXED, __HIP_MEMORY_SCOPE_AGENT);
                    if (t == TT - 1) {
                        out[YOFF + (size_t)b * HH + hbase + g] = h;                 // h_n[0]
                        out[YOFF + 2 * BB * HH + (size_t)b * HH + hbase + g] = c;   // c_n[0]
                    }
                } else {
                    __hip_atomic_store(&HP1[widx], packed,
                                       __ATOMIC_RELAXED, __HIP_MEMORY_SCOPE_AGENT);
                    if (s == TT) {   // last step: no barrier follows, store now
                        out[((size_t)b * TT + t) * HH + hbase + g] = h;             // y
                        out[YOFF + BB * HH + (size_t)b * HH + hbase + g] = h;       // h_n[1]
                        out[YOFF + 3 * BB * HH + (size_t)b * HH + hbase + g] = c;   // c_n[1]
                    } else {
                        hdef = h;    // defer y to after the flag store
                    }
                }
            }
        }
        // ---- flat flag barrier: store-only, per-block monotonic epochs ----
        if (s < TT) {
            __syncthreads();   // drains each thread's vmcnt -> h stores visible
            ++epoch;
            if (tid == 0) {
                asm volatile("s_waitcnt vmcnt(0)" ::: "memory");
                __hip_atomic_store(&bar[bid], epoch,
                                   __ATOMIC_RELAXED, __HIP_MEMORY_SCOPE_AGENT);
            }
            if (layer && active && tid < 256) {   // y store drains during poll
                const int b = tid >> 2, g = tid & 3;
                out[((size_t)b * TT + (s - 1)) * HH + hbase + g] = hdef;
            }
            if (tid < 256) {   // 4 waves, each poll covers 64 consecutive flags
                while (__hip_atomic_load(&bar[tid], __ATOMIC_RELAXED,
                                         __HIP_MEMORY_SCOPE_AGENT) < epoch)
                    __builtin_amdgcn_s_sleep(1);
            }
            __syncthreads();
        }
    }
}

extern "C" void kernel_launch(void* const* d_in, const int* in_sizes, int n_in,
                              void* d_out, int out_size, void* d_ws, size_t ws_size,
                              hipStream_t stream) {
    (void)in_sizes; (void)n_in; (void)out_size; (void)ws_size;
    const float* x  = (const float*)d_in[0];
    const float* W0 = (const float*)d_in[1];
    const float* b0 = (const float*)d_in[2];
    const float* W1 = (const float*)d_in[3];
    const float* b1 = (const float*)d_in[4];
    float* out = (float*)d_out;
    unsigned* hws = (unsigned*)d_ws;  // 2 buffers x [2][128][64][4] u32 = 512 KB
    unsigned* bar = (unsigned*)((char*)d_ws + 2 * 2 * 64 * 512 * sizeof(unsigned));

    hipMemsetAsync(d_ws, 0, 2 * 2 * 64 * 512 * sizeof(unsigned) + 4096, stream);

    void* args[] = { (void*)&x, (void*)&W0, (void*)&b0, (void*)&W1, (void*)&b1,
                     (void*)&out, (void*)&hws, (void*)&bar };
    hipLaunchCooperativeKernel(reinterpret_cast<const void*>(lstm_fused),
                               dim3(256), dim3(512), args, 0u, stream);
}

// Round 4
// 8799.376 us; speedup vs baseline: 1.3258x; 1.2606x over previous
//
#include <hip/hip_runtime.h>

// 2-layer LSTM, B=64, T=1024, D_IN=256, H=512, fp32 in/out.
// R7: repartition to cut L3 broadcast traffic (the R4/R6-neutrality-implied
// bottleneck). Traffic = (gate_rows/M_t) * K * 64b * 4B, independent of N-split:
//   old: M_t=16 (4 hidden x 64 b per block)  -> 48 MB/step from L3
//   new: M_t=32, N_t=32 (8 hidden x 32 b)    -> 24 MB/step, same 256 blocks
// Per-wave MFMA count unchanged (48); W frags 64 + raw 64 + acc 16 VGPRs.
// Memory model identical to R4/R6 (verified): sc1 agent reads of h, relaxed
// agent write-through h stores, flat store-only flag barrier, deferred y store.

#define BB   64
#define TT   1024
#define DIN  256
#define HH   512
#define K0   768     // [h0_prev(512) | x_t(256)]
#define K1   1024    // [h1_prev(512) | h0_t(512)]
#define NTHR 512

typedef float f32x4 __attribute__((ext_vector_type(4)));
typedef short short8 __attribute__((ext_vector_type(8)));
typedef unsigned uint4v __attribute__((ext_vector_type(4)));

union S8U4 { short8 s; unsigned u[4]; };
union RawU { unsigned u[8]; uint4v q[2]; f32x4 v[2]; };  // 8 packed h words OR 8 x floats

__device__ __forceinline__ void splitf(float f, short& h, short& l) {
    const unsigned u = __float_as_uint(f);
    const float fh = __uint_as_float(u & 0xffff0000u);
    h = (short)(u >> 16);
    l = (short)(__float_as_uint(f - fh) >> 16);
}

__device__ __forceinline__ void split8(f32x4 a, f32x4 b, short8& hi, short8& lo) {
#pragma unroll
    for (int j = 0; j < 4; ++j) {
        short h0, l0, h1, l1;
        splitf(a[j], h0, l0);
        splitf(b[j], h1, l1);
        hi[j] = h0; lo[j] = l0;
        hi[j + 4] = h1; lo[j + 4] = l1;
    }
}

__device__ __forceinline__ unsigned packhl(float f) {
    const unsigned u = __float_as_uint(f);
    const float fh = __uint_as_float(u & 0xffff0000u);
    const unsigned l = __float_as_uint(f - fh) >> 16;
    return (u >> 16) | (l << 16);     // bytes 0-1: hi bf16, bytes 2-3: lo bf16
}

// sc1 = agent-scope (bypass stale L1/L2, served by L3) -- verified R3/R4/R6.
#define LDX4(dst, ptr, off) \
    asm volatile("global_load_dwordx4 %0, %1, off offset:" #off " sc1" \
                 : "=v"(dst) : "v"(ptr) : "memory")

// One k-step (32 k) for both n-tiles (32 b): nt stride 256B, k-tile pair 1024B.
#define LD4(A, R) do { \
    LDX4((R)[0].q[0], (A), 0);    LDX4((R)[0].q[1], (A), 1024); \
    LDX4((R)[1].q[0], (A), 256);  LDX4((R)[1].q[1], (A), 1280); \
} while (0)

__global__ __launch_bounds__(NTHR, 2) void lstm_fused(
    const float* __restrict__ x,
    const float* __restrict__ W0, const float* __restrict__ b0v,
    const float* __restrict__ W1, const float* __restrict__ b1v,
    float* __restrict__ out, unsigned* __restrict__ hws, unsigned* __restrict__ bar)
{
    __shared__ float Red[8][32][33];    // per-wave K-partials (33.8 KB)
    __shared__ float Gb[32][36];        // gates regroup, padded (4.6 KB)
    __shared__ float biasl[32];

    const int tid   = threadIdx.x;
    const int bid   = blockIdx.x;
    const int layer = bid >> 7;
    const int mgrp  = (bid & 127) >> 1;
    const int nh    = bid & 1;
    const int hbase = mgrp << 3;       // 8 hidden rows per block
    const int nbase = nh << 5;         // 32 batches per block

    const float* Wm = layer ? W1 : W0;
    const float* bv = layer ? b1v : b0v;
    const int K     = layer ? K1 : K0;

    // packed (hi|lo) h buffers, tiled: [2 parities][k>>2][64 b][k&3] u32
    unsigned* HP0 = hws;
    unsigned* HP1 = hws + 2 * BB * HH;

    if (tid < 32)
        biasl[tid] = bv[(tid >> 3) * HH + hbase + (tid & 7)];

    const int w     = tid >> 6;        // wave 0..7 (K-slice owner)
    const int lane  = tid & 63;
    const int quad  = lane >> 4;       // 0..3
    const int lm    = lane & 15;       // fragment row (m or n)
    const int kbase = w << 7;          // wave's K offset (128 each)
    const bool isx  = (!layer && kbase >= HH);   // L0 waves 4,5 (x); 6,7 idle

    // ---- persistent W fragments: [mt][ks], hi/lo bf16 ----
    short8 whi[2][4], wlo[2][4];
#pragma unroll
    for (int mt = 0; mt < 2; ++mt)
#pragma unroll
        for (int ks = 0; ks < 4; ++ks) {
            short8 hi = {0, 0, 0, 0, 0, 0, 0, 0};
            short8 lo = {0, 0, 0, 0, 0, 0, 0, 0};
            const int kb = kbase + ks * 32;
            if (kb < K) {
                const int k0 = kb + quad * 8;
                const int r  = mt * 16 + lm;          // gate-row in [0,32)
                const int grow = (r >> 3) * HH + hbase + (r & 7);
                const float* p = Wm + (size_t)grow * K + k0;
                split8(*(const f32x4*)p, *(const f32x4*)(p + 4), hi, lo);
            }
            whi[mt][ks] = hi; wlo[mt][ks] = lo;
        }
    __syncthreads();

    float creg = 0.0f;                 // persistent cell state (tid<256)
    unsigned epoch = 0;
    const size_t YOFF = (size_t)BB * TT * HH;

    for (int s = 0; s <= TT; ++s) {
        const bool active = layer ? (s >= 1) : (s < TT);
        float hdef = 0.0f;             // deferred y value (layer 1)
        if (active) {
            const int t = layer ? (s - 1) : s;
            const unsigned par = (unsigned)(s & 1) * (BB * HH);
            const unsigned* hp = (layer ? HP1 : HP0) + par;
            const unsigned* hc = HP0 + par;   // layer1: h0 of current t

            // ---- PHASE 1: issue ALL loads (asm outputs pin full prefetch) ----
            RawU raw[4][2];   // [ks][nt]
            if (layer || kbase < HH) {         // h-type wave
                const unsigned* src; int kk;
                if (!layer || kbase < HH) { src = hp; kk = kbase; }
                else                      { src = hc; kk = kbase - HH; }
                if (layer && kbase >= HH) { src = hc; kk = kbase - HH; }
                // byte addr = kk*256 + quad*2048 + (nbase+lm)*16 (+ks*8192 +imm)
                const char* A = (const char*)src + ((size_t)kk << 8)
                              + (quad << 11) + ((nbase + lm) << 4);
                LD4(A,         raw[0]);
                LD4(A + 8192,  raw[1]);
                LD4(A + 16384, raw[2]);
                LD4(A + 24576, raw[3]);
            } else if (isx) {                  // x waves (plain cached loads)
#pragma unroll
                for (int ks = 0; ks < 4; ++ks) {
                    const int kb = kbase + ks * 32;
                    if (kb < K0) {
                        const int k0 = kb + quad * 8;
#pragma unroll
                        for (int nt = 0; nt < 2; ++nt) {
                            const int bg = nbase + (nt << 4) + lm;
                            const float* p = x + ((size_t)bg * TT + t) * DIN + (k0 - HH);
                            raw[ks][nt].v[0] = *(const f32x4*)p;
                            raw[ks][nt].v[1] = *(const f32x4*)(p + 4);
                        }
                    }
                }
            }
            asm volatile("s_waitcnt vmcnt(0)" ::: "memory");
            __builtin_amdgcn_sched_barrier(0);   // rule #18

            // ---- PHASE 2: unpack + MFMA ----
            f32x4 acc[2][2];
#pragma unroll
            for (int mt = 0; mt < 2; ++mt)
#pragma unroll
                for (int nt = 0; nt < 2; ++nt)
                    acc[mt][nt] = (f32x4){0.f, 0.f, 0.f, 0.f};

#pragma unroll
            for (int ks = 0; ks < 4; ++ks) {
                const int kb = kbase + ks * 32;
                if (kb < K) {
#pragma unroll
                    for (int nt = 0; nt < 2; ++nt) {
                        short8 chi, clo;
                        if (isx) {
                            split8(raw[ks][nt].v[0], raw[ks][nt].v[1], chi, clo);
                        } else {
                            S8U4 hi, lo;
#pragma unroll
                            for (int j2 = 0; j2 < 4; ++j2) {
                                const unsigned u0 = raw[ks][nt].u[2 * j2];
                                const unsigned u1 = raw[ks][nt].u[2 * j2 + 1];
                                hi.u[j2] = __builtin_amdgcn_perm(u1, u0, 0x05040100u);
                                lo.u[j2] = __builtin_amdgcn_perm(u1, u0, 0x07060302u);
                            }
                            chi = hi.s; clo = lo.s;
                        }
#pragma unroll
                        for (int mt = 0; mt < 2; ++mt) {
                            acc[mt][nt] = __builtin_amdgcn_mfma_f32_16x16x32_bf16(whi[mt][ks], chi, acc[mt][nt], 0, 0, 0);
                            acc[mt][nt] = __builtin_amdgcn_mfma_f32_16x16x32_bf16(whi[mt][ks], clo, acc[mt][nt], 0, 0, 0);
                            acc[mt][nt] = __builtin_amdgcn_mfma_f32_16x16x32_bf16(wlo[mt][ks], chi, acc[mt][nt], 0, 0, 0);
                        }
                    }
                }
            }

            // ---- dump K-partials: D[row=mt*16+quad*4+r][col=nt*16+lm] ----
#pragma unroll
            for (int mt = 0; mt < 2; ++mt)
#pragma unroll
                for (int nt = 0; nt < 2; ++nt)
#pragma unroll
                    for (int r = 0; r < 4; ++r)
                        Red[w][mt * 16 + quad * 4 + r][(nt << 4) + lm] = acc[mt][nt][r];
            __syncthreads();
            // ---- 8-way reduce + bias: 512 threads, 2 outputs each ----
            {
                const int row = tid >> 5;      // 0..15
                const int bc  = tid & 31;
                float s0 = biasl[row], s1 = biasl[row + 16];
#pragma unroll
                for (int ww = 0; ww < 8; ++ww) {
                    s0 += Red[ww][row][bc];
                    s1 += Red[ww][row + 16][bc];
                }
                Gb[bc][row] = s0;
                Gb[bc][row + 16] = s1;
            }
            __syncthreads();
            // ---- cell: 256 threads, (b=tid>>3, hh=tid&7); c in creg ----
            if (tid < 256) {
                const int b  = tid >> 3;          // local batch 0..31
                const int hh = tid & 7;           // local hidden 0..7
                const int bglob = nbase + b;
                const float ig = Gb[b][hh];
                const float fg = Gb[b][8 + hh];
                const float gg = Gb[b][16 + hh];
                const float og = Gb[b][24 + hh];
                const float si = 1.0f / (1.0f + __expf(-ig));
                const float sf = 1.0f / (1.0f + __expf(-fg));
                const float so = 1.0f / (1.0f + __expf(-og));
                const float c  = sf * creg + si * tanhf(gg);
                creg = c;
                const float h  = so * tanhf(c);
                const int hidx = hbase + hh;
                const unsigned wpar = (unsigned)((s + 1) & 1) * (BB * HH);
                // tiled store: [k>>2][b][k&3]
                const unsigned widx = wpar + (((unsigned)hidx >> 2) << 8)
                                    + ((unsigned)bglob << 2) + (hh & 3);
                const unsigned packed = packhl(h);
                if (layer == 0) {
                    __hip_atomic_store(&HP0[widx], packed,
                                       __ATOMIC_RELAXED, __HIP_MEMORY_SCOPE_AGENT);
                    if (t == TT - 1) {
                        out[YOFF + (size_t)bglob * HH + hidx] = h;                 // h_n[0]
                        out[YOFF + 2 * BB * HH + (size_t)bglob * HH + hidx] = c;   // c_n[0]
                    }
                } else {
                    __hip_atomic_store(&HP1[widx], packed,
                                       __ATOMIC_RELAXED, __HIP_MEMORY_SCOPE_AGENT);
                    if (s == TT) {   // last step: no barrier follows, store now
                        out[((size_t)bglob * TT + t) * HH + hidx] = h;             // y
                        out[YOFF + BB * HH + (size_t)bglob * HH + hidx] = h;       // h_n[1]
                        out[YOFF + 3 * BB * HH + (size_t)bglob * HH + hidx] = c;   // c_n[1]
                    } else {
                        hdef = h;    // defer y to after the flag store
                    }
                }
            }
        }
        // ---- flat flag barrier: store-only, per-block monotonic epochs ----
        if (s < TT) {
            __syncthreads();   // drains each thread's vmcnt -> h stores visible
            ++epoch;
            if (tid == 0) {
                asm volatile("s_waitcnt vmcnt(0)" ::: "memory");
                __hip_atomic_store(&bar[bid], epoch,
                                   __ATOMIC_RELAXED, __HIP_MEMORY_SCOPE_AGENT);
            }
            if (layer && active && tid < 256) {   // y store drains during poll
                const int b = tid >> 3, hh = tid & 7;
                out[((size_t)(nbase + b) * TT + (s - 1)) * HH + hbase + hh] = hdef;
            }
            if (tid < 256) {   // 4 waves, each poll covers 64 consecutive flags
                while (__hip_atomic_load(&bar[tid], __ATOMIC_RELAXED,
                                         __HIP_MEMORY_SCOPE_AGENT) < epoch)
                    __builtin_amdgcn_s_sleep(1);
            }
            __syncthreads();
        }
    }
}

extern "C" void kernel_launch(void* const* d_in, const int* in_sizes, int n_in,
                              void* d_out, int out_size, void* d_ws, size_t ws_size,
                              hipStream_t stream) {
    (void)in_sizes; (void)n_in; (void)out_size; (void)ws_size;
    const float* x  = (const float*)d_in[0];
    const float* W0 = (const float*)d_in[1];
    const float* b0 = (const float*)d_in[2];
    const float* W1 = (const float*)d_in[3];
    const float* b1 = (const float*)d_in[4];
    float* out = (float*)d_out;
    unsigned* hws = (unsigned*)d_ws;  // 2 buffers x [2][128][64][4] u32 = 512 KB
    unsigned* bar = (unsigned*)((char*)d_ws + 2 * 2 * 64 * 512 * sizeof(unsigned));

    hipMemsetAsync(d_ws, 0, 2 * 2 * 64 * 512 * sizeof(unsigned) + 4096, stream);

    void* args[] = { (void*)&x, (void*)&W0, (void*)&b0, (void*)&W1, (void*)&b1,
                     (void*)&out, (void*)&hws, (void*)&bar };
    hipLaunchCooperativeKernel(reinterpret_cast<const void*>(lstm_fused),
                               dim3(256), dim3(512), args, 0u, stream);
}

// Round 6
// 6316.573 us; speedup vs baseline: 1.8469x; 1.3931x over previous
//
#include <hip/hip_runtime.h>

// 2-layer LSTM, B=64, T=1024, D_IN=256, H=512, fp32 in/out.
// R8 RERUN (previous round was an infra failure: "container failed twice",
// no profile, no verdict; source re-audited, no hang path found).
// R8: third halving of L3 broadcast traffic via taller M-tile.
//   R6: M_t=16 -> 48 MB/step; R7: M_t=32 -> 24 MB/step (dur -21%);
//   R8: M_t=64, N_t=16 (16 hidden x 16 batch per block) -> 12.6 MB/step.
// Grid unchanged: 256 blocks (128/layer = 32 m-groups x 4 batch-quarters),
// 512 thr, 1 block/CU. Per-wave MFMA count unchanged (48). Plus: layer-0
// x-waves prefetch next-t x during the barrier poll window (their vmcnt is
// drained by the pre-s_barrier wait while the block idles in the poll).
// Memory model identical to R4/R6/R7 (verified): sc1 agent reads of h,
// relaxed agent write-through h stores, flat store-only flag barrier,
// deferred y store after the flag store.

#define BB   64
#define TT   1024
#define DIN  256
#define HH   512
#define K0   768     // [h0_prev(512) | x_t(256)]
#define K1   1024    // [h1_prev(512) | h0_t(512)]
#define NTHR 512

typedef float f32x4 __attribute__((ext_vector_type(4)));
typedef short short8 __attribute__((ext_vector_type(8)));
typedef unsigned uint4v __attribute__((ext_vector_type(4)));

union S8U4 { short8 s; unsigned u[4]; };
union RawU { unsigned u[8]; uint4v q[2]; f32x4 v[2]; };  // 8 packed h words OR 8 x floats

__device__ __forceinline__ void splitf(float f, short& h, short& l) {
    const unsigned u = __float_as_uint(f);
    const float fh = __uint_as_float(u & 0xffff0000u);
    h = (short)(u >> 16);
    l = (short)(__float_as_uint(f - fh) >> 16);
}

__device__ __forceinline__ void split8(f32x4 a, f32x4 b, short8& hi, short8& lo) {
#pragma unroll
    for (int j = 0; j < 4; ++j) {
        short h0, l0, h1, l1;
        splitf(a[j], h0, l0);
        splitf(b[j], h1, l1);
        hi[j] = h0; lo[j] = l0;
        hi[j + 4] = h1; lo[j + 4] = l1;
    }
}

__device__ __forceinline__ unsigned packhl(float f) {
    const unsigned u = __float_as_uint(f);
    const float fh = __uint_as_float(u & 0xffff0000u);
    const unsigned l = __float_as_uint(f - fh) >> 16;
    return (u >> 16) | (l << 16);     // bytes 0-1: hi bf16, bytes 2-3: lo bf16
}

// sc1 = agent-scope (bypass stale L1/L2, served by L3) -- verified R3..R7.
#define LDX4(dst, ptr, off) \
    asm volatile("global_load_dwordx4 %0, %1, off offset:" #off " sc1" \
                 : "=v"(dst) : "v"(ptr) : "memory")

// One k-step (32 k) for the single 16-batch n-tile: two k-halves 1024B apart.
#define LD2(A, R) do { \
    LDX4((R).q[0], (A), 0);  LDX4((R).q[1], (A), 1024); \
} while (0)

// x loads (plain cached) for one step, layer-0 x-waves only.
__device__ __forceinline__ void load_x(const float* __restrict__ x, int t,
                                       int nbase, int lm, int kbase, int quad,
                                       RawU raw[4]) {
#pragma unroll
    for (int ks = 0; ks < 4; ++ks) {
        const int kb = kbase + ks * 32;
        if (kb < K0) {
            const int k0 = kb + quad * 8;
            const int bg = nbase + lm;
            const float* p = x + ((size_t)bg * TT + t) * DIN + (k0 - HH);
            raw[ks].v[0] = *(const f32x4*)p;
            raw[ks].v[1] = *(const f32x4*)(p + 4);
        }
    }
}

__global__ __launch_bounds__(NTHR, 2) void lstm_fused(
    const float* __restrict__ x,
    const float* __restrict__ W0, const float* __restrict__ b0v,
    const float* __restrict__ W1, const float* __restrict__ b1v,
    float* __restrict__ out, unsigned* __restrict__ hws, unsigned* __restrict__ bar)
{
    __shared__ float Red[8][64][17];    // per-wave K-partials (34.8 KB)
    __shared__ float Gb[16][68];        // gates regroup, padded (4.4 KB)
    __shared__ float biasl[64];

    const int tid   = threadIdx.x;
    const int bid   = blockIdx.x;
    const int layer = bid >> 7;
    const int mgrp  = (bid & 127) >> 2;
    const int nq    = bid & 3;
    const int hbase = mgrp << 4;       // 16 hidden rows per block
    const int nbase = nq << 4;         // 16 batches per block

    const float* Wm = layer ? W1 : W0;
    const float* bv = layer ? b1v : b0v;
    const int K     = layer ? K1 : K0;

    // packed (hi|lo) h buffers, tiled: [2 parities][k>>2][64 b][k&3] u32
    unsigned* HP0 = hws;
    unsigned* HP1 = hws + 2 * BB * HH;

    if (tid < 64)
        biasl[tid] = bv[(tid >> 4) * HH + hbase + (tid & 15)];

    const int w     = tid >> 6;        // wave 0..7 (K-slice owner)
    const int lane  = tid & 63;
    const int quad  = lane >> 4;       // 0..3
    const int lm    = lane & 15;       // fragment row (m or n)
    const int kbase = w << 7;          // wave's K offset (128 each)
    const bool isx  = (!layer && kbase >= HH);   // L0 waves 4,5 (x); 6,7 idle
    const bool ish  = (layer || kbase < HH);     // h-type wave

    // ---- persistent W fragments: [mt][ks], hi/lo bf16 (128 VGPRs) ----
    short8 whi[4][4], wlo[4][4];
#pragma unroll
    for (int mt = 0; mt < 4; ++mt)
#pragma unroll
        for (int ks = 0; ks < 4; ++ks) {
            short8 hi = {0, 0, 0, 0, 0, 0, 0, 0};
            short8 lo = {0, 0, 0, 0, 0, 0, 0, 0};
            const int kb = kbase + ks * 32;
            if (kb < K) {
                const int k0 = kb + quad * 8;
                const int r  = mt * 16 + lm;          // gate-row in [0,64)
                const int grow = (r >> 4) * HH + hbase + (r & 15);
                const float* p = Wm + (size_t)grow * K + k0;
                split8(*(const f32x4*)p, *(const f32x4*)(p + 4), hi, lo);
            }
            whi[mt][ks] = hi; wlo[mt][ks] = lo;
        }
    __syncthreads();

    float creg = 0.0f;                 // persistent cell state (tid<256)
    unsigned epoch = 0;
    const size_t YOFF = (size_t)BB * TT * HH;

    RawU raw[4];                       // [ks]; persists across barrier for x
    if (isx) load_x(x, 0, nbase, lm, kbase, quad, raw);   // s=0 prefetch

    for (int s = 0; s <= TT; ++s) {
        const bool active = layer ? (s >= 1) : (s < TT);
        float hdef = 0.0f;             // deferred y value (layer 1)
        if (active) {
            const unsigned par = (unsigned)(s & 1) * (BB * HH);
            const unsigned* hp = (layer ? HP1 : HP0) + par;
            const unsigned* hc = HP0 + par;   // layer1: h0 of current t

            // ---- PHASE 1: h loads (x already prefetched during poll) ----
            if (ish) {
                const unsigned* src; int kk;
                if (kbase < HH) { src = hp; kk = kbase; }        // own prev h
                else            { src = hc; kk = kbase - HH; }   // L1: h0 cur
                // byte addr = kk*256 + quad*2048 + (nbase+lm)*16 (+ks*8192+imm)
                const char* A = (const char*)src + ((size_t)kk << 8)
                              + (quad << 11) + ((nbase + lm) << 4);
                LD2(A,         raw[0]);
                LD2(A + 8192,  raw[1]);
                LD2(A + 16384, raw[2]);
                LD2(A + 24576, raw[3]);
            }
            asm volatile("s_waitcnt vmcnt(0)" ::: "memory");
            __builtin_amdgcn_sched_barrier(0);   // rule #18

            // ---- PHASE 2: unpack + MFMA ----
            f32x4 acc[4];
#pragma unroll
            for (int mt = 0; mt < 4; ++mt) acc[mt] = (f32x4){0.f, 0.f, 0.f, 0.f};

#pragma unroll
            for (int ks = 0; ks < 4; ++ks) {
                const int kb = kbase + ks * 32;
                if (kb < K) {
                    short8 chi, clo;
                    if (isx) {
                        split8(raw[ks].v[0], raw[ks].v[1], chi, clo);
                    } else {
                        S8U4 hi, lo;
#pragma unroll
                        for (int j2 = 0; j2 < 4; ++j2) {
                            const unsigned u0 = raw[ks].u[2 * j2];
                            const unsigned u1 = raw[ks].u[2 * j2 + 1];
                            hi.u[j2] = __builtin_amdgcn_perm(u1, u0, 0x05040100u);
                            lo.u[j2] = __builtin_amdgcn_perm(u1, u0, 0x07060302u);
                        }
                        chi = hi.s; clo = lo.s;
                    }
#pragma unroll
                    for (int mt = 0; mt < 4; ++mt) {
                        acc[mt] = __builtin_amdgcn_mfma_f32_16x16x32_bf16(whi[mt][ks], chi, acc[mt], 0, 0, 0);
                        acc[mt] = __builtin_amdgcn_mfma_f32_16x16x32_bf16(whi[mt][ks], clo, acc[mt], 0, 0, 0);
                        acc[mt] = __builtin_amdgcn_mfma_f32_16x16x32_bf16(wlo[mt][ks], chi, acc[mt], 0, 0, 0);
                    }
                }
            }

            // ---- dump K-partials: D[row=mt*16+quad*4+r][col=lm] ----
#pragma unroll
            for (int mt = 0; mt < 4; ++mt)
#pragma unroll
                for (int r = 0; r < 4; ++r)
                    Red[w][mt * 16 + quad * 4 + r][lm] = acc[mt][r];
            __syncthreads();
            // ---- 8-way reduce + bias: 512 threads, 2 outputs each ----
            {
                const int row = tid >> 4;      // 0..31 (handles row, row+32)
                const int bc  = tid & 15;
                float s0 = biasl[row], s1 = biasl[row + 32];
#pragma unroll
                for (int ww = 0; ww < 8; ++ww) {
                    s0 += Red[ww][row][bc];
                    s1 += Red[ww][row + 32][bc];
                }
                Gb[bc][row] = s0;
                Gb[bc][row + 32] = s1;
            }
            __syncthreads();
            // ---- cell: 256 threads, (b=tid>>4, hh=tid&15); c in creg ----
            if (tid < 256) {
                const int t  = layer ? (s - 1) : s;
                const int b  = tid >> 4;          // local batch 0..15
                const int hh = tid & 15;          // local hidden 0..15
                const int bglob = nbase + b;
                const float ig = Gb[b][hh];
                const float fg = Gb[b][16 + hh];
                const float gg = Gb[b][32 + hh];
                const float og = Gb[b][48 + hh];
                const float si = 1.0f / (1.0f + __expf(-ig));
                const float sf = 1.0f / (1.0f + __expf(-fg));
                const float so = 1.0f / (1.0f + __expf(-og));
                const float c  = sf * creg + si * tanhf(gg);
                creg = c;
                const float h  = so * tanhf(c);
                const int hidx = hbase + hh;
                const unsigned wpar = (unsigned)((s + 1) & 1) * (BB * HH);
                // tiled store: [k>>2][b][k&3]
                const unsigned widx = wpar + (((unsigned)hidx >> 2) << 8)
                                    + ((unsigned)bglob << 2) + (hidx & 3);
                const unsigned packed = packhl(h);
                if (layer == 0) {
                    __hip_atomic_store(&HP0[widx], packed,
                                       __ATOMIC_RELAXED, __HIP_MEMORY_SCOPE_AGENT);
                    if (t == TT - 1) {
                        out[YOFF + (size_t)bglob * HH + hidx] = h;                 // h_n[0]
                        out[YOFF + 2 * BB * HH + (size_t)bglob * HH + hidx] = c;   // c_n[0]
                    }
                } else {
                    __hip_atomic_store(&HP1[widx], packed,
                                       __ATOMIC_RELAXED, __HIP_MEMORY_SCOPE_AGENT);
                    if (s == TT) {   // last step: no barrier follows, store now
                        out[((size_t)bglob * TT + t) * HH + hidx] = h;             // y
                        out[YOFF + BB * HH + (size_t)bglob * HH + hidx] = h;       // h_n[1]
                        out[YOFF + 3 * BB * HH + (size_t)bglob * HH + hidx] = c;   // c_n[1]
                    } else {
                        hdef = h;    // defer y to after the flag store
                    }
                }
            }
        }
        // ---- flat flag barrier: store-only, per-block monotonic epochs ----
        if (s < TT) {
            __syncthreads();   // drains each thread's vmcnt -> h stores visible
            ++epoch;
            if (tid == 0) {
                asm volatile("s_waitcnt vmcnt(0)" ::: "memory");
                __hip_atomic_store(&bar[bid], epoch,
                                   __ATOMIC_RELAXED, __HIP_MEMORY_SCOPE_AGENT);
            }
            if (layer && active && tid < 256) {   // y store drains during poll
                const int b = tid >> 4, hh = tid & 15;
                out[((size_t)(nbase + b) * TT + (s - 1)) * HH + hbase + hh] = hdef;
            }
            // x-waves (tid 256..383) prefetch next-t x; drained by the implicit
            // vmcnt(0) before the closing s_barrier -- i.e. during the poll.
            if (isx && s + 1 < TT)
                load_x(x, s + 1, nbase, lm, kbase, quad, raw);
            if (tid < 256) {   // 4 waves, each poll covers 64 consecutive flags
                while (__hip_atomic_load(&bar[tid], __ATOMIC_RELAXED,
                                         __HIP_MEMORY_SCOPE_AGENT) < epoch)
                    __builtin_amdgcn_s_sleep(1);
            }
            __syncthreads();
        }
    }
}

extern "C" void kernel_launch(void* const* d_in, const int* in_sizes, int n_in,
                              void* d_out, int out_size, void* d_ws, size_t ws_size,
                              hipStream_t stream) {
    (void)in_sizes; (void)n_in; (void)out_size; (void)ws_size;
    const float* x  = (const float*)d_in[0];
    const float* W0 = (const float*)d_in[1];
    const float* b0 = (const float*)d_in[2];
    const float* W1 = (const float*)d_in[3];
    const float* b1 = (const float*)d_in[4];
    float* out = (float*)d_out;
    unsigned* hws = (unsigned*)d_ws;  // 2 buffers x [2][128][64][4] u32 = 512 KB
    unsigned* bar = (unsigned*)((char*)d_ws + 2 * 2 * 64 * 512 * sizeof(unsigned));

    hipMemsetAsync(d_ws, 0, 2 * 2 * 64 * 512 * sizeof(unsigned) + 4096, stream);

    void* args[] = { (void*)&x, (void*)&W0, (void*)&b0, (void*)&W1, (void*)&b1,
                     (void*)&out, (void*)&hws, (void*)&bar };
    hipLaunchCooperativeKernel(reinterpret_cast<const void*>(lstm_fused),
                               dim3(256), dim3(512), args, 0u, stream);
}

// Round 7
// 4671.625 us; speedup vs baseline: 2.4972x; 1.3521x over previous
//
#include <hip/hip_runtime.h>

// 2-layer LSTM, B=64, T=1024, D_IN=256, H=512, fp32 in/out.
// R9: decouple the global barrier.
//  - The 4 batch-quarters are fully independent (block (mgrp,nq) only ever
//    reads h produced by blocks with the same nq). The 2 layers couple
//    one-directionally with 1 step of parity slack.
//  - Replace the 256-block global barrier with per-(quarter,layer) monotonic
//    flag sets of 32: L0 step t waits {A0>=t, A1>=t-1}; L1 step t waits
//    {A1>=t, A0>=t+1}. L0 runs ~1 step ahead, so L1's A0 wait is pre-satisfied
//    and the L0->L1 handoff round trip leaves the critical path.
//  - Fused reduce+cell: cell thread (b,hh) sums its 32 K-partials directly
//    from Red (drops the Gb pass and one __syncthreads).
//  - Red pad 17->20: MFMA-dump quad stride becomes bank+16 -> 2-way (free)
//    instead of 4-way conflicts.
// Memory model identical to R4..R8 (verified): sc1 agent reads of h, relaxed
// agent write-through h stores, __syncthreads (implicit per-wave vmcnt drain)
// before the flag store, store-only monotonic flags, x-prefetch + y stores
// overlapped with the poll window.

#define BB   64
#define TT   1024
#define DIN  256
#define HH   512
#define K0   768     // [h0_prev(512) | x_t(256)]
#define K1   1024    // [h1_prev(512) | h0_t(512)]
#define NTHR 512

typedef float f32x4 __attribute__((ext_vector_type(4)));
typedef short short8 __attribute__((ext_vector_type(8)));
typedef unsigned uint4v __attribute__((ext_vector_type(4)));

union S8U4 { short8 s; unsigned u[4]; };
union RawU { unsigned u[8]; uint4v q[2]; f32x4 v[2]; };  // 8 packed h words OR 8 x floats

__device__ __forceinline__ void splitf(float f, short& h, short& l) {
    const unsigned u = __float_as_uint(f);
    const float fh = __uint_as_float(u & 0xffff0000u);
    h = (short)(u >> 16);
    l = (short)(__float_as_uint(f - fh) >> 16);
}

__device__ __forceinline__ void split8(f32x4 a, f32x4 b, short8& hi, short8& lo) {
#pragma unroll
    for (int j = 0; j < 4; ++j) {
        short h0, l0, h1, l1;
        splitf(a[j], h0, l0);
        splitf(b[j], h1, l1);
        hi[j] = h0; lo[j] = l0;
        hi[j + 4] = h1; lo[j + 4] = l1;
    }
}

__device__ __forceinline__ unsigned packhl(float f) {
    const unsigned u = __float_as_uint(f);
    const float fh = __uint_as_float(u & 0xffff0000u);
    const unsigned l = __float_as_uint(f - fh) >> 16;
    return (u >> 16) | (l << 16);     // bytes 0-1: hi bf16, bytes 2-3: lo bf16
}

// sc1 = agent-scope (bypass stale L1/L2, served by L3) -- verified R3..R8.
#define LDX4(dst, ptr, off) \
    asm volatile("global_load_dwordx4 %0, %1, off offset:" #off " sc1" \
                 : "=v"(dst) : "v"(ptr) : "memory")

// One k-step (32 k) for the single 16-batch n-tile: two k-halves 1024B apart.
#define LD2(A, R) do { \
    LDX4((R).q[0], (A), 0);  LDX4((R).q[1], (A), 1024); \
} while (0)

// x loads (plain cached) for one step, layer-0 x-waves only.
__device__ __forceinline__ void load_x(const float* __restrict__ x, int t,
                                       int nbase, int lm, int kbase, int quad,
                                       RawU raw[4]) {
#pragma unroll
    for (int ks = 0; ks < 4; ++ks) {
        const int kb = kbase + ks * 32;
        if (kb < K0) {
            const int k0 = kb + quad * 8;
            const int bg = nbase + lm;
            const float* p = x + ((size_t)bg * TT + t) * DIN + (k0 - HH);
            raw[ks].v[0] = *(const f32x4*)p;
            raw[ks].v[1] = *(const f32x4*)(p + 4);
        }
    }
}

__global__ __launch_bounds__(NTHR, 2) void lstm_fused(
    const float* __restrict__ x,
    const float* __restrict__ W0, const float* __restrict__ b0v,
    const float* __restrict__ W1, const float* __restrict__ b1v,
    float* __restrict__ out, unsigned* __restrict__ hws, unsigned* __restrict__ bar)
{
    __shared__ float Red[8][64][20];    // per-wave K-partials, pad 20 (40 KB)
    __shared__ float biasl[64];

    const int tid   = threadIdx.x;
    const int bid   = blockIdx.x;
    const int layer = bid >> 7;
    const int mgrp  = (bid & 127) >> 2;
    const int g     = bid & 3;         // batch-quarter group
    const int hbase = mgrp << 4;       // 16 hidden rows per block
    const int nbase = g << 4;          // 16 batches per block

    const float* Wm = layer ? W1 : W0;
    const float* bv = layer ? b1v : b0v;
    const int K     = layer ? K1 : K0;

    // packed (hi|lo) h buffers, tiled: [2 parities][k>>2][64 b][k&3] u32
    unsigned* HP0 = hws;
    unsigned* HP1 = hws + 2 * BB * HH;
    // flags: bar[g*64 + layer*32 + mgrp], monotonic step counters
    unsigned* fOwn = bar + g * 64 + layer * 32;
    unsigned* fOth = bar + g * 64 + (1 - layer) * 32;

    if (tid < 64)
        biasl[tid] = bv[(tid >> 4) * HH + hbase + (tid & 15)];

    const int w     = tid >> 6;        // wave 0..7 (K-slice owner)
    const int lane  = tid & 63;
    const int quad  = lane >> 4;       // 0..3
    const int lm    = lane & 15;       // fragment row (m or n)
    const int kbase = w << 7;          // wave's K offset (128 each)
    const bool isx  = (!layer && kbase >= HH);   // L0 waves 4,5 (x); 6,7 idle
    const bool ish  = (layer || kbase < HH);     // h-type wave

    // ---- persistent W fragments: [mt][ks], hi/lo bf16 (128 VGPRs) ----
    short8 whi[4][4], wlo[4][4];
#pragma unroll
    for (int mt = 0; mt < 4; ++mt)
#pragma unroll
        for (int ks = 0; ks < 4; ++ks) {
            short8 hi = {0, 0, 0, 0, 0, 0, 0, 0};
            short8 lo = {0, 0, 0, 0, 0, 0, 0, 0};
            const int kb = kbase + ks * 32;
            if (kb < K) {
                const int k0 = kb + quad * 8;
                const int r  = mt * 16 + lm;          // gate-row in [0,64)
                const int grow = (r >> 4) * HH + hbase + (r & 15);
                const float* p = Wm + (size_t)grow * K + k0;
                split8(*(const f32x4*)p, *(const f32x4*)(p + 4), hi, lo);
            }
            whi[mt][ks] = hi; wlo[mt][ks] = lo;
        }
    __syncthreads();

    float creg = 0.0f;                 // persistent cell state (tid<256)
    const size_t YOFF = (size_t)BB * TT * HH;

    RawU raw[4];                       // [ks]; persists across iters for x
    if (isx) load_x(x, 0, nbase, lm, kbase, quad, raw);   // t=0 prefetch

    for (int t = 0; t < TT; ++t) {
        // ---- input wait: two waves poll two 32-flag sets ----
        {
            const int own_tgt = t;                       // own layer done t-1
            const int oth_tgt = layer ? (t + 1) : (t - 1);
            if (tid < 32) {
                while ((int)__hip_atomic_load(&fOwn[tid], __ATOMIC_RELAXED,
                                              __HIP_MEMORY_SCOPE_AGENT) < own_tgt)
                    __builtin_amdgcn_s_sleep(1);
            } else if (tid >= 64 && tid < 96) {
                while ((int)__hip_atomic_load(&fOth[tid - 64], __ATOMIC_RELAXED,
                                              __HIP_MEMORY_SCOPE_AGENT) < oth_tgt)
                    __builtin_amdgcn_s_sleep(1);
            }
            __syncthreads();
        }
        const unsigned rpar = (unsigned)((t + 1) & 1) * (BB * HH);  // h[t-1]
        const unsigned cpar = (unsigned)(t & 1) * (BB * HH);        // h[t] (write; L1 reads h0[t])

        // ---- PHASE 1: h loads (x already prefetched during poll) ----
        if (ish) {
            const unsigned* src; int kk;
            if (kbase < HH) { src = (layer ? HP1 : HP0) + rpar; kk = kbase; }
            else            { src = HP0 + cpar; kk = kbase - HH; }   // L1: h0[t]
            // byte addr = kk*256 + quad*2048 + (nbase+lm)*16 (+ks*8192+imm)
            const char* A = (const char*)src + ((size_t)kk << 8)
                          + (quad << 11) + ((nbase + lm) << 4);
            LD2(A,         raw[0]);
            LD2(A + 8192,  raw[1]);
            LD2(A + 16384, raw[2]);
            LD2(A + 24576, raw[3]);
        }
        asm volatile("s_waitcnt vmcnt(0)" ::: "memory");
        __builtin_amdgcn_sched_barrier(0);   // rule #18

        // ---- PHASE 2: unpack + MFMA ----
        f32x4 acc[4];
#pragma unroll
        for (int mt = 0; mt < 4; ++mt) acc[mt] = (f32x4){0.f, 0.f, 0.f, 0.f};

#pragma unroll
        for (int ks = 0; ks < 4; ++ks) {
            const int kb = kbase + ks * 32;
            if (kb < K) {
                short8 chi, clo;
                if (isx) {
                    split8(raw[ks].v[0], raw[ks].v[1], chi, clo);
                } else {
                    S8U4 hi, lo;
#pragma unroll
                    for (int j2 = 0; j2 < 4; ++j2) {
                        const unsigned u0 = raw[ks].u[2 * j2];
                        const unsigned u1 = raw[ks].u[2 * j2 + 1];
                        hi.u[j2] = __builtin_amdgcn_perm(u1, u0, 0x05040100u);
                        lo.u[j2] = __builtin_amdgcn_perm(u1, u0, 0x07060302u);
                    }
                    chi = hi.s; clo = lo.s;
                }
#pragma unroll
                for (int mt = 0; mt < 4; ++mt) {
                    acc[mt] = __builtin_amdgcn_mfma_f32_16x16x32_bf16(whi[mt][ks], chi, acc[mt], 0, 0, 0);
                    acc[mt] = __builtin_amdgcn_mfma_f32_16x16x32_bf16(whi[mt][ks], clo, acc[mt], 0, 0, 0);
                    acc[mt] = __builtin_amdgcn_mfma_f32_16x16x32_bf16(wlo[mt][ks], chi, acc[mt], 0, 0, 0);
                }
            }
        }

        // ---- dump K-partials: D[row=mt*16+quad*4+r][col=lm] ----
#pragma unroll
        for (int mt = 0; mt < 4; ++mt)
#pragma unroll
            for (int r = 0; r < 4; ++r)
                Red[w][mt * 16 + quad * 4 + r][lm] = acc[mt][r];
        __syncthreads();

        // ---- fused 8-way reduce + bias + cell (tid<256) ----
        float hdef = 0.0f, cdef = 0.0f;
        if (tid < 256) {
            const int b  = tid >> 4;          // local batch 0..15
            const int hh = tid & 15;          // local hidden 0..15
            float gsum[4];
#pragma unroll
            for (int g4 = 0; g4 < 4; ++g4) {
                float sgate = biasl[g4 * 16 + hh];
#pragma unroll
                for (int ww = 0; ww < 8; ++ww)
                    sgate += Red[ww][g4 * 16 + hh][b];
                gsum[g4] = sgate;
            }
            const float si = 1.0f / (1.0f + __expf(-gsum[0]));
            const float sf = 1.0f / (1.0f + __expf(-gsum[1]));
            const float so = 1.0f / (1.0f + __expf(-gsum[3]));
            const float c  = sf * creg + si * tanhf(gsum[2]);
            creg = c;
            const float h  = so * tanhf(c);
            hdef = h; cdef = c;
            const int hidx  = hbase + hh;
            const int bglob = nbase + b;
            const unsigned widx = cpar + (((unsigned)hidx >> 2) << 8)
                                + ((unsigned)bglob << 2) + (hidx & 3);
            __hip_atomic_store(&(layer ? HP1 : HP0)[widx], packhl(h),
                               __ATOMIC_RELAXED, __HIP_MEMORY_SCOPE_AGENT);
        }
        __syncthreads();   // drains each wave's vmcnt -> h stores visible (L3)

        if (tid == 0) {
            asm volatile("s_waitcnt vmcnt(0)" ::: "memory");
            __hip_atomic_store(&fOwn[mgrp], (unsigned)(t + 1),
                               __ATOMIC_RELAXED, __HIP_MEMORY_SCOPE_AGENT);
        }
        // ---- outputs + x prefetch: overlap with next iteration's poll ----
        if (tid < 256) {
            const int b = tid >> 4, hh = tid & 15;
            const int bglob = nbase + b, hidx = hbase + hh;
            if (layer)
                out[((size_t)bglob * TT + t) * HH + hidx] = hdef;     // y[b,t,:]
            if (t == TT - 1) {
                if (layer == 0) {
                    out[YOFF + (size_t)bglob * HH + hidx] = hdef;                 // h_n[0]
                    out[YOFF + 2 * BB * HH + (size_t)bglob * HH + hidx] = cdef;   // c_n[0]
                } else {
                    out[YOFF + BB * HH + (size_t)bglob * HH + hidx] = hdef;       // h_n[1]
                    out[YOFF + 3 * BB * HH + (size_t)bglob * HH + hidx] = cdef;   // c_n[1]
                }
            }
        }
        if (isx && t + 1 < TT)
            load_x(x, t + 1, nbase, lm, kbase, quad, raw);
    }
}

extern "C" void kernel_launch(void* const* d_in, const int* in_sizes, int n_in,
                              void* d_out, int out_size, void* d_ws, size_t ws_size,
                              hipStream_t stream) {
    (void)in_sizes; (void)n_in; (void)out_size; (void)ws_size;
    const float* x  = (const float*)d_in[0];
    const float* W0 = (const float*)d_in[1];
    const float* b0 = (const float*)d_in[2];
    const float* W1 = (const float*)d_in[3];
    const float* b1 = (const float*)d_in[4];
    float* out = (float*)d_out;
    unsigned* hws = (unsigned*)d_ws;  // 2 buffers x [2][128][64][4] u32 = 512 KB
    unsigned* bar = (unsigned*)((char*)d_ws + 2 * 2 * 64 * 512 * sizeof(unsigned));

    hipMemsetAsync(d_ws, 0, 2 * 2 * 64 * 512 * sizeof(unsigned) + 4096, stream);

    void* args[] = { (void*)&x, (void*)&W0, (void*)&b0, (void*)&W1, (void*)&b1,
                     (void*)&out, (void*)&hws, (void*)&bar };
    hipLaunchCooperativeKernel(reinterpret_cast<const void*>(lstm_fused),
                               dim3(256), dim3(512), args, 0u, stream);
}

// Round 9
// 3962.951 us; speedup vs baseline: 2.9438x; 1.1788x over previous
//
#include <hip/hip_runtime.h>

// 2-layer LSTM, B=64, T=1024, D_IN=256, H=512, fp32 in/out.
// R11: flagless self-validating recurrence (replaces R10's withdrawn sc0/L2
// experiment -- that path relied on unverified cross-CU sc0 coherence and is
// a hang risk; this one uses ONLY the R3..R9-verified primitives).
//  - Each packed h word (hi bf16 | lo bf16) donates the 3 low mantissa bits of
//    lo as an epoch tag: tag = (t%7)+1 (never 0 => never aliases the zeroed
//    buffer; ring stride 4 or 3 is coprime-safe vs mod 7). Error ~2^-18 rel.
//  - Consumers issue h loads SPECULATIVELY (sc1) and retry until all 32 words
//    carry the expected tag. No flag round trip, no ordering assumptions:
//    every 4B word self-describes freshness (word stores are atomic).
//  - h rings deepened to 4 slots (3 if ws is tight): producer at t+1 writes
//    over h[t-3]; group skew is data-bounded at <=1 so overwrite-during-read
//    is impossible. Cross-layer guard: L1 posts a progress flag (no drain
//    needed -- it asserts reads-done); L0 polls it with ring-1 steps of slack
//    (off the critical path).
//  - Red double-buffered -> ONE __syncthreads per step.
//  - All spin loops are capped: a logic bug surfaces as absmax-fail, not hang.
//  - ws_size-gated: ring=4 (1MB+4K), ring=3 (768K+4K), else EXACT R9 fallback.

#define BB   64
#define TT   1024
#define DIN  256
#define HH   512
#define K0   768     // [h0_prev(512) | x_t(256)]
#define K1   1024    // [h1_prev(512) | h0_t(512)]
#define NTHR 512
#define SL   (BB * HH)          // u32 per h slice (128 KB)

typedef float f32x4 __attribute__((ext_vector_type(4)));
typedef short short8 __attribute__((ext_vector_type(8)));
typedef unsigned uint4v __attribute__((ext_vector_type(4)));

union S8U4 { short8 s; unsigned u[4]; };
union RawU { unsigned u[8]; uint4v q[2]; f32x4 v[2]; };

__device__ __forceinline__ void splitf(float f, short& h, short& l) {
    const unsigned u = __float_as_uint(f);
    const float fh = __uint_as_float(u & 0xffff0000u);
    h = (short)(u >> 16);
    l = (short)(__float_as_uint(f - fh) >> 16);
}

__device__ __forceinline__ void split8(f32x4 a, f32x4 b, short8& hi, short8& lo) {
#pragma unroll
    for (int j = 0; j < 4; ++j) {
        short h0, l0, h1, l1;
        splitf(a[j], h0, l0);
        splitf(b[j], h1, l1);
        hi[j] = h0; lo[j] = l0;
        hi[j + 4] = h1; lo[j + 4] = l1;
    }
}

__device__ __forceinline__ unsigned packhl(float f) {
    const unsigned u = __float_as_uint(f);
    const float fh = __uint_as_float(u & 0xffff0000u);
    const unsigned l = __float_as_uint(f - fh) >> 16;
    return (u >> 16) | (l << 16);   // bits 0-15: hi bf16, bits 16-31: lo bf16
}

// sc1: agent scope (bypass stale L1/L2, served by L3) -- verified R3..R9.
#define LDX4(dst, ptr, off) \
    asm volatile("global_load_dwordx4 %0, %1, off offset:" #off " sc1" \
                 : "=v"(dst) : "v"(ptr) : "memory")
#define LD2(A, R) do { LDX4((R).q[0], (A), 0); LDX4((R).q[1], (A), 1024); } while (0)

__device__ __forceinline__ void load_h(const char* A, RawU raw[4]) {
    LD2(A,         raw[0]);
    LD2(A + 8192,  raw[1]);
    LD2(A + 16384, raw[2]);
    LD2(A + 24576, raw[3]);
}

// OR of ((word>>16) ^ etag) & 7 over all 32 words: 0 iff all tags match.
__device__ __forceinline__ unsigned tagbad(const RawU raw[4], unsigned etag16) {
    unsigned bad = 0;
#pragma unroll
    for (int ks = 0; ks < 4; ++ks)
#pragma unroll
        for (int j = 0; j < 8; ++j)
            bad |= (raw[ks].u[j] ^ etag16) & 0x00070000u;
    return bad;
}

__device__ __forceinline__ void load_x(const float* __restrict__ x, int t,
                                       int nbase, int lm, int kbase, int quad,
                                       RawU raw[4]) {
#pragma unroll
    for (int ks = 0; ks < 4; ++ks) {
        const int kb = kbase + ks * 32;
        if (kb < K0) {
            const int k0 = kb + quad * 8;
            const int bg = nbase + lm;
            const float* p = x + ((size_t)bg * TT + t) * DIN + (k0 - HH);
            raw[ks].v[0] = *(const f32x4*)p;
            raw[ks].v[1] = *(const f32x4*)(p + 4);
        }
    }
}

__global__ __launch_bounds__(NTHR, 2) void lstm_fused(
    const float* __restrict__ x,
    const float* __restrict__ W0, const float* __restrict__ b0v,
    const float* __restrict__ W1, const float* __restrict__ b1v,
    float* __restrict__ out, unsigned* __restrict__ hws,
    unsigned* __restrict__ bar, int ring)
{
    __shared__ float Red[2][8][64][20];   // double-buffered K-partials (80 KB)
    __shared__ float biasl[64];

    const int tid   = threadIdx.x;
    const int bid   = blockIdx.x;
    const int layer = bid >> 7;
    const int mgrp  = (bid & 127) >> 2;
    const int g     = bid & 3;
    const int hbase = mgrp << 4;       // 16 hidden rows per block
    const int nbase = g << 4;          // 16 batches per block

    const float* Wm = layer ? W1 : W0;
    const float* bv = layer ? b1v : b0v;
    const int K     = layer ? K1 : K0;

    unsigned* HP0 = hws;
    unsigned* HP1 = hws + (unsigned)(ring ? ring : 2) * SL;
    const unsigned fidx = ((unsigned)layer << 7) + ((unsigned)g << 5);

    if (tid < 64)
        biasl[tid] = bv[(tid >> 4) * HH + hbase + (tid & 15)];

    const int w     = tid >> 6;
    const int lane  = tid & 63;
    const int quad  = lane >> 4;
    const int lm    = lane & 15;
    const int kbase = w << 7;
    const bool isx  = (!layer && kbase >= HH && kbase < K0);
    const bool ish  = (layer || kbase < HH);

    // ---- persistent W fragments ----
    short8 whi[4][4], wlo[4][4];
#pragma unroll
    for (int mt = 0; mt < 4; ++mt)
#pragma unroll
        for (int ks = 0; ks < 4; ++ks) {
            short8 hi = {0, 0, 0, 0, 0, 0, 0, 0};
            short8 lo = {0, 0, 0, 0, 0, 0, 0, 0};
            const int kb = kbase + ks * 32;
            if (kb < K) {
                const int k0 = kb + quad * 8;
                const int r  = mt * 16 + lm;
                const int grow = (r >> 4) * HH + hbase + (r & 15);
                const float* p = Wm + (size_t)grow * K + k0;
                split8(*(const f32x4*)p, *(const f32x4*)(p + 4), hi, lo);
            }
            whi[mt][ks] = hi; wlo[mt][ks] = lo;
        }
    __syncthreads();

    float creg = 0.0f;
    const size_t YOFF = (size_t)BB * TT * HH;

    RawU raw[4];
    if (isx) load_x(x, 0, nbase, lm, kbase, quad, raw);

    for (int t = 0; t < TT; ++t) {
        // ---- fallback (ring==0): exact R9 input wait ----
        if (!ring) {
            const int own_tgt = t;
            const int oth_tgt = layer ? (t + 1) : (t - 1);
            const unsigned oidx = ((unsigned)(1 - layer) << 7) + ((unsigned)g << 5);
            if (tid < 32) {
                while ((int)__hip_atomic_load(&bar[fidx + tid], __ATOMIC_RELAXED,
                                              __HIP_MEMORY_SCOPE_AGENT) < own_tgt)
                    __builtin_amdgcn_s_sleep(1);
            } else if (tid >= 64 && tid < 96) {
                while ((int)__hip_atomic_load(&bar[oidx + (tid - 64)], __ATOMIC_RELAXED,
                                              __HIP_MEMORY_SCOPE_AGENT) < oth_tgt)
                    __builtin_amdgcn_s_sleep(1);
            }
            __syncthreads();
        }

        // ring slots: read h[t-1] (own) / h0[t] (L1 cross); write h[t]
        unsigned rslot, cslot;
        if (ring == 4)      { rslot = (t + 3) & 3; cslot = t & 3; }
        else if (ring == 3) { rslot = (t + 2) % 3; cslot = t % 3; }
        else                { rslot = (t + 1) & 1; cslot = t & 1; }

        // ---- PHASE 1: speculative h loads ----
        const char* A = nullptr;
        bool val0c = false;
        if (ish) {
            const unsigned* src; int kk;
            if (kbase < HH) { src = (layer ? HP1 : HP0) + rslot * SL; kk = kbase; }
            else            { src = HP0 + cslot * SL; kk = kbase - HH; val0c = true; }
            A = (const char*)src + ((size_t)kk << 8) + (quad << 11) + ((nbase + lm) << 4);
            load_h(A, raw);
        }
        // L0 overwrite guard (ring mode): poll L1 progress with ring-1 slack,
        // overlapped with the load flight; gates the h0 store via the sync.
        if (ring && !layer && w == 0) {
            const int tgt = t - (ring - 1);
            if (tgt > 0) {
                const unsigned gbase = 128u + ((unsigned)g << 5);
                int spins = 0;
                while (true) {
                    const unsigned f = __hip_atomic_load(&bar[gbase + (lane & 31)],
                                           __ATOMIC_RELAXED, __HIP_MEMORY_SCOPE_AGENT);
                    if (!__any((int)f < tgt)) break;
                    if (++spins > 1000000) break;
                    __builtin_amdgcn_s_sleep(8);
                }
            }
        }
        asm volatile("s_waitcnt vmcnt(0)" ::: "memory");
        __builtin_amdgcn_sched_barrier(0);   // rule #18

        // ---- tag validate + retry (ring mode) ----
        if (ring && ish && (val0c || t >= 1)) {
            const unsigned etag16 =
                (unsigned)((val0c ? (t % 7) : ((t + 6) % 7)) + 1) << 16;
            unsigned bad = tagbad(raw, etag16);
            int spins = 0;
            while (__any((int)bad)) {
                if (++spins > 4000) break;      // bug => absmax fail, not hang
                __builtin_amdgcn_s_sleep(1);
                load_h(A, raw);
                asm volatile("s_waitcnt vmcnt(0)" ::: "memory");
                __builtin_amdgcn_sched_barrier(0);
                bad = tagbad(raw, etag16);
            }
        }

        // ---- PHASE 2: unpack + MFMA ----
        f32x4 acc[4];
#pragma unroll
        for (int mt = 0; mt < 4; ++mt) acc[mt] = (f32x4){0.f, 0.f, 0.f, 0.f};

#pragma unroll
        for (int ks = 0; ks < 4; ++ks) {
            const int kb = kbase + ks * 32;
            if (kb < K) {
                short8 chi, clo;
                if (isx) {
                    split8(raw[ks].v[0], raw[ks].v[1], chi, clo);
                } else {
                    S8U4 hi, lo;
#pragma unroll
                    for (int j2 = 0; j2 < 4; ++j2) {
                        const unsigned u0 = raw[ks].u[2 * j2];
                        const unsigned u1 = raw[ks].u[2 * j2 + 1];
                        hi.u[j2] = __builtin_amdgcn_perm(u1, u0, 0x05040100u);
                        lo.u[j2] = __builtin_amdgcn_perm(u1, u0, 0x07060302u);
                    }
                    chi = hi.s; clo = lo.s;
                }
#pragma unroll
                for (int mt = 0; mt < 4; ++mt) {
                    acc[mt] = __builtin_amdgcn_mfma_f32_16x16x32_bf16(whi[mt][ks], chi, acc[mt], 0, 0, 0);
                    acc[mt] = __builtin_amdgcn_mfma_f32_16x16x32_bf16(whi[mt][ks], clo, acc[mt], 0, 0, 0);
                    acc[mt] = __builtin_amdgcn_mfma_f32_16x16x32_bf16(wlo[mt][ks], chi, acc[mt], 0, 0, 0);
                }
            }
        }

        // ---- dump K-partials into Red[t&1] ----
        const int rb = t & 1;
#pragma unroll
        for (int mt = 0; mt < 4; ++mt)
#pragma unroll
            for (int r = 0; r < 4; ++r)
                Red[rb][w][mt * 16 + quad * 4 + r][lm] = acc[mt][r];
        __syncthreads();

        // ring mode: L1 posts progress (asserts reads-done; no drain needed)
        if (ring && layer && tid == 0)
            __hip_atomic_store(&bar[fidx + mgrp], (unsigned)(t + 1),
                               __ATOMIC_RELAXED, __HIP_MEMORY_SCOPE_AGENT);

        // ---- fused 8-way reduce + bias + cell ----
        float hdef = 0.0f;
        if (tid < 256) {
            const int b  = tid >> 4;
            const int hh = tid & 15;
            float gsum[4];
#pragma unroll
            for (int g4 = 0; g4 < 4; ++g4) {
                float sgate = biasl[g4 * 16 + hh];
#pragma unroll
                for (int ww = 0; ww < 8; ++ww)
                    sgate += Red[rb][ww][g4 * 16 + hh][b];
                gsum[g4] = sgate;
            }
            const float si = 1.0f / (1.0f + __expf(-gsum[0]));
            const float sf = 1.0f / (1.0f + __expf(-gsum[1]));
            const float so = 1.0f / (1.0f + __expf(-gsum[3]));
            const float c  = sf * creg + si * tanhf(gsum[2]);
            creg = c;
            const float h  = so * tanhf(c);
            hdef = h;
            const int hidx  = hbase + hh;
            const int bglob = nbase + b;
            const unsigned widx = (((unsigned)hidx >> 2) << 8)
                                + ((unsigned)bglob << 2) + (hidx & 3);
            unsigned packed = packhl(h);
            if (ring)   // embed epoch tag in lo-bf16 low mantissa bits
                packed = (packed & 0xFFF8FFFFu) | ((unsigned)((t % 7) + 1) << 16);
            __hip_atomic_store(&(layer ? HP1 : HP0)[cslot * SL + widx], packed,
                               __ATOMIC_RELAXED, __HIP_MEMORY_SCOPE_AGENT);
            if (ring && layer)
                out[((size_t)bglob * TT + t) * HH + hidx] = h;
            if (t == TT - 1) {
                if (layer == 0) {
                    out[YOFF + (size_t)bglob * HH + hidx] = h;
                    out[YOFF + 2 * BB * HH + (size_t)bglob * HH + hidx] = c;
                } else {
                    out[YOFF + BB * HH + (size_t)bglob * HH + hidx] = h;
                    out[YOFF + 3 * BB * HH + (size_t)bglob * HH + hidx] = c;
                }
            }
        }

        // ---- fallback (ring==0): R9 flag post + deferred y ----
        if (!ring) {
            __syncthreads();
            if (tid == 0) {
                asm volatile("s_waitcnt vmcnt(0)" ::: "memory");
                __hip_atomic_store(&bar[fidx + mgrp], (unsigned)(t + 1),
                                   __ATOMIC_RELAXED, __HIP_MEMORY_SCOPE_AGENT);
            }
            if (layer && tid < 256) {
                const int b = tid >> 4, hh = tid & 15;
                out[((size_t)(nbase + b) * TT + t) * HH + hbase + hh] = hdef;
            }
        }
        if (isx && t + 1 < TT)
            load_x(x, t + 1, nbase, lm, kbase, quad, raw);
    }
}

extern "C" void kernel_launch(void* const* d_in, const int* in_sizes, int n_in,
                              void* d_out, int out_size, void* d_ws, size_t ws_size,
                              hipStream_t stream) {
    (void)in_sizes; (void)n_in; (void)out_size;
    const float* x  = (const float*)d_in[0];
    const float* W0 = (const float*)d_in[1];
    const float* b0 = (const float*)d_in[2];
    const float* W1 = (const float*)d_in[3];
    const float* b1 = (const float*)d_in[4];
    float* out = (float*)d_out;
    unsigned* hws = (unsigned*)d_ws;

    const size_t b4 = (size_t)8 * SL * 4 + 4096;    // ring 4: 1 MB + 4 KB
    const size_t b3 = (size_t)6 * SL * 4 + 4096;    // ring 3: 768 KB + 4 KB
    const size_t b0sz = (size_t)4 * SL * 4 + 4096;  // fallback (R9): 512 KB + 4 KB
    int ring; size_t clr;
    if (ws_size >= b4)      { ring = 4; clr = b4; }
    else if (ws_size >= b3) { ring = 3; clr = b3; }
    else                    { ring = 0; clr = b0sz; }
    unsigned* bar = (unsigned*)((char*)d_ws + clr - 4096);

    hipMemsetAsync(d_ws, 0, clr, stream);

    void* args[] = { (void*)&x, (void*)&W0, (void*)&b0, (void*)&W1, (void*)&b1,
                     (void*)&out, (void*)&hws, (void*)&bar, (void*)&ring };
    hipLaunchCooperativeKernel(reinterpret_cast<const void*>(lstm_fused),
                               dim3(256), dim3(512), args, 0u, stream);
}